// Round 3
// baseline (50.766 us; speedup 1.0000x reference)
//
#include <hip/hip_runtime.h>

// out[b, k] = in[b, TRI_I[k]] * in[b, TRI_J[k]], k over strictly-lower-tri
// (i>j) pairs of a 512x512 matrix in row-major (i,j) order.
// B=512, N=512, NC2 = 512*511/2 = 130816.

#define N_ATOMS 512
#define NC2     130816
#define NQ4     (NC2 / 4)   // 32704 float4 stores per batch row

typedef float fvec4 __attribute__((ext_vector_type(4)));  // native vec for nontemporal store

// Skewed LDS index: bank = (t + t/32) % 32, so lane patterns j = j0 + 4*lane
// (our access shape) hit all 32 banks instead of 8 (8-way conflict).
__device__ __forceinline__ int skew(int t) { return t + (t >> 5); }

__global__ __launch_bounds__(256) void ncp_kernel(const float* __restrict__ in,
                                                  float* __restrict__ out) {
    __shared__ float row[N_ATOMS + (N_ATOMS >> 5)];   // 528 floats
    const int b   = blockIdx.y;
    const int tid = threadIdx.x;

    // Stage this batch's 512-float row into LDS at skewed indices.
    {
        const float2* src = reinterpret_cast<const float2*>(in + (size_t)b * N_ATOMS);
        float2 v = src[tid];
        const int t = 2 * tid;          // t and t+1 share the same skew offset
        row[skew(t)]     = v.x;
        row[skew(t) + 1] = v.y;
    }
    __syncthreads();

    fvec4* outb = reinterpret_cast<fvec4*>(out + (size_t)b * NC2);

    for (int q = blockIdx.x * 256 + tid; q < NQ4; q += gridDim.x * 256) {
        const int k = q * 4;

        // i = floor((1 + sqrt(8k+1)) / 2), with integer fix-up for sqrtf
        // rounding at triangular-number boundaries.
        int i = (int)(0.5f * (1.0f + sqrtf(8.0f * (float)k + 1.0f)));
        while (i * (i - 1) / 2 > k)       --i;
        while ((i + 1) * i / 2 <= k)      ++i;
        int j = k - i * (i - 1) / 2;

        float ri = row[skew(i)];
        fvec4 v;
#pragma unroll
        for (int t = 0; t < 4; ++t) {
            v[t] = ri * row[skew(j)];
            if (++j == i) { ++i; j = 0; ri = row[skew(i)]; }
        }
        __builtin_nontemporal_store(v, &outb[q]);
    }
}

extern "C" void kernel_launch(void* const* d_in, const int* in_sizes, int n_in,
                              void* d_out, int out_size, void* d_ws, size_t ws_size,
                              hipStream_t stream) {
    const float* atom_nc = (const float*)d_in[0];
    float* out = (float*)d_out;

    dim3 grid(32, 512);   // 32 chunks per batch x 512 batches
    dim3 block(256);
    ncp_kernel<<<grid, block, 0, stream>>>(atom_nc, out);
}

// Round 4
// 45.920 us; speedup vs baseline: 1.1055x; 1.1055x over previous
//
#include <hip/hip_runtime.h>

// out[b, k] = in[b, TRI_I[k]] * in[b, TRI_J[k]], k over strictly-lower-tri
// (i>j) pairs of a 512x512 matrix in row-major (i,j) order.
// B=512, N=512, NC2 = 512*511/2 = 130816.

#define N_ATOMS 512
#define NC2     130816
#define NQ4     (NC2 / 4)   // 32704 float4 stores per batch row

// Skewed LDS index: bank = (t + t/32) % 32. Our read pattern is
// j = j0 + 4*lane across the wave; unskewed that hits only 8 banks
// (8-way conflict, ~2.9x cost). Skewed it covers all 32 banks, 2 lanes
// each (2-way aliasing is free on CDNA4).
__device__ __forceinline__ int skew(int t) { return t + (t >> 5); }

__global__ __launch_bounds__(256) void ncp_kernel(const float* __restrict__ in,
                                                  float* __restrict__ out) {
    __shared__ float row[N_ATOMS + (N_ATOMS >> 5)];   // 528 floats
    const int b   = blockIdx.y;
    const int tid = threadIdx.x;

    // Stage this batch's 512-float row into LDS at skewed indices.
    {
        const float2* src = reinterpret_cast<const float2*>(in + (size_t)b * N_ATOMS);
        float2 v = src[tid];
        const int t = 2 * tid;          // t even: skew(t)+1 == skew(t+1)
        row[skew(t)]     = v.x;
        row[skew(t) + 1] = v.y;
    }
    __syncthreads();

    float4* outb = reinterpret_cast<float4*>(out + (size_t)b * NC2);

    for (int q = blockIdx.x * 256 + tid; q < NQ4; q += gridDim.x * 256) {
        const int k = q * 4;

        // i = floor((1 + sqrt(8k+1)) / 2), with integer fix-up for sqrtf
        // rounding at triangular-number boundaries.
        int i = (int)(0.5f * (1.0f + sqrtf(8.0f * (float)k + 1.0f)));
        while (i * (i - 1) / 2 > k)       --i;
        while ((i + 1) * i / 2 <= k)      ++i;
        int j = k - i * (i - 1) / 2;

        float ri = row[skew(i)];
        float4 v;
        float* vp = &v.x;
#pragma unroll
        for (int t = 0; t < 4; ++t) {
            vp[t] = ri * row[skew(j)];
            if (++j == i) { ++i; j = 0; ri = row[skew(i)]; }
        }
        outb[q] = v;
    }
}

extern "C" void kernel_launch(void* const* d_in, const int* in_sizes, int n_in,
                              void* d_out, int out_size, void* d_ws, size_t ws_size,
                              hipStream_t stream) {
    const float* atom_nc = (const float*)d_in[0];
    float* out = (float*)d_out;

    dim3 grid(32, 512);   // 32 chunks per batch x 512 batches
    dim3 block(256);
    ncp_kernel<<<grid, block, 0, stream>>>(atom_nc, out);
}

// Round 5
// 45.646 us; speedup vs baseline: 1.1122x; 1.0060x over previous
//
#include <hip/hip_runtime.h>

// out[b, k] = in[b, TRI_I[k]] * in[b, TRI_J[k]], k over strictly-lower-tri
// (i>j) pairs of a 512x512 matrix, row-major (i,j) order.
// B=512, N=512, NC2 = 512*511/2 = 130816.

#define N_ATOMS 512
#define NC2     130816
#define NQ4     (NC2 / 4)   // 32704 float4 stores per batch row
#define GX      32          // blocks per batch (compile-time!)
#define NITER   4           // 32*256*4 = 32768 >= 32704

// Skewed LDS index: bank = (t + t/32) % 32 — keeps the 4-stride lane
// pattern conflict-free (2-way, which is free on CDNA4).
__device__ __forceinline__ int skew(int t) { return t + (t >> 5); }

__global__ __launch_bounds__(256, 8)
void ncp_kernel(const float* __restrict__ in, float* __restrict__ out) {
    __shared__ float row[N_ATOMS + (N_ATOMS >> 5) + 8];   // 536 floats
    const int b   = blockIdx.y;
    const int tid = threadIdx.x;

    // Stage this batch's 512-float row into LDS at skewed indices.
    {
        const float2* src = reinterpret_cast<const float2*>(in + (size_t)b * N_ATOMS);
        float2 v = src[tid];
        const int t = 2 * tid;          // t even: skew(t)+1 == skew(t+1)
        row[skew(t)]     = v.x;
        row[skew(t) + 1] = v.y;
    }
    __syncthreads();

    float4* outb = reinterpret_cast<float4*>(out + (size_t)b * NC2);
    const int q0 = blockIdx.x * 256 + tid;

#pragma unroll
    for (int s = 0; s < NITER; ++s) {
        const int q = q0 + s * (GX * 256);
        if (q < NQ4) {
            const int k = q * 4;

            // i estimate: 8k+1 < 2^20 is exact in fp32, sqrtf correctly
            // rounded -> estimate off by at most 1 -> single-step fixup,
            // branchless (if-convertible).
            int i  = (int)(0.5f * (1.0f + sqrtf(8.0f * (float)k + 1.0f)));
            int t2 = (i * (i - 1)) >> 1;
            if (t2 > k)           { t2 -= --i; }   // i too big:  tri(i-1) = t2-(i-1)
            else if (k >= t2 + i) { t2 += i++; }   // i too small: tri(i+1) = t2+i
            int j = k - t2;

            float ri = row[skew(i)];
            float4 v;
            v.x = ri * row[skew(j)];
            { ++j; bool c = (j == i); i += c; j = c ? 0 : j; ri = row[skew(i)]; }
            v.y = ri * row[skew(j)];
            { ++j; bool c = (j == i); i += c; j = c ? 0 : j; ri = row[skew(i)]; }
            v.z = ri * row[skew(j)];
            { ++j; bool c = (j == i); i += c; j = c ? 0 : j; ri = row[skew(i)]; }
            v.w = ri * row[skew(j)];

            outb[q] = v;
        }
    }
}

extern "C" void kernel_launch(void* const* d_in, const int* in_sizes, int n_in,
                              void* d_out, int out_size, void* d_ws, size_t ws_size,
                              hipStream_t stream) {
    const float* atom_nc = (const float*)d_in[0];
    float* out = (float*)d_out;

    dim3 grid(GX, 512);
    dim3 block(256);
    ncp_kernel<<<grid, block, 0, stream>>>(atom_nc, out);
}